// Round 2
// baseline (77723.462 us; speedup 1.0000x reference)
//
#include <hip/hip_runtime.h>
#include <math.h>

#define BB   64      // batch
#define TT_  1024    // sequence length
#define UU   512     // hidden units
#define VV   256     // vocab (output)
#define EE   256     // embedding dim
#define TC   64      // time chunk
#define NBG  32      // batch groups (2 batches each)
#define NUG  8       // unit groups (64 units each)
#define FLG_INTS (NBG * 2 * NUG * 4)   // 2048 flags

__device__ __forceinline__ float tanh_fast(float x) {
    // tanh(x) = 1 - 2/(e^{2x}+1); rcp is 1-ulp, expf ~2-ulp -> abs err ~1e-6
    float e = __expf(x + x);
    return 1.f - 2.f * __builtin_amdgcn_rcpf(e + 1.f);
}

// ---------------- E2 = emb @ Wx + b : [256, 512] ----------------
__global__ __launch_bounds__(512) void e2_kernel(
    const float* __restrict__ emb, const float* __restrict__ Wx,
    const float* __restrict__ bias, float* __restrict__ E2)
{
    const int v = blockIdx.x;
    const int u = threadIdx.x;
    float acc = bias[u];
    const float* er = emb + v * EE;
    #pragma unroll 8
    for (int e = 0; e < EE; ++e)
        acc = fmaf(er[e], Wx[e * UU + u], acc);
    E2[v * UU + u] = acc;
}

// ---------------- recurrence: Wh in VGPRs, flag-sync h exchange ----------------
// 256 blocks = 32 bg x 8 ug (blockIdx = ug*32+bg for XCD locality).
// 512 threads = 8 waves. Wave w: batch b = w>>2, w4 = w&3.
// Lane: kg = lane&15 (32 k each), u4s = lane>>4; u4g = 4*w4+u4s (4 units).
__global__ __launch_bounds__(512, 2) void rnn_chunk_kernel(
    const int* __restrict__ toks, const float* __restrict__ E2,
    const float* __restrict__ Wh, float* hglob,   // [2][BB][UU]
    int* flg,                                     // [BB][NUG][4]
    float* __restrict__ hs, int t0)
{
    const int bid  = blockIdx.x;
    const int bg   = bid & 31;
    const int ug   = bid >> 5;
    const int tid  = threadIdx.x;
    const int w    = tid >> 6;
    const int lane = tid & 63;
    const int kg   = lane & 15;
    const int u4s  = lane >> 4;
    const int b    = w >> 2;
    const int w4   = w & 3;
    const int u4g  = 4 * w4 + u4s;
    const int bglob = bg * 2 + b;
    const int uf4  = ug * 16 + u4g;        // float4 column index of my 4 units

    // --- Wh slice into registers: whr[kk] = Wh[kg*32+kk][4 units] ---
    const float4* Wh4 = (const float4*)Wh;   // [512][128]
    float4 whr[32];
    #pragma unroll
    for (int kk = 0; kk < 32; ++kk)
        whr[kk] = Wh4[(kg * 32 + kk) * 128 + uf4];

    const float4* E24 = (const float4*)E2;   // [256][128]
    float4* hg4 = (float4*)hglob;            // 2 x 8192 float4
    int* myflag = flg + bglob * 32 + ug * 4 + w4;
    int* cflg   = flg + bglob * 32;          // 32 producer flags for my batch

    for (int tt = 0; tt < TC; ++tt) {
        const int s = t0 + tt;
        const int tok = toks[bglob * TT_ + s];
        float4 xp = make_float4(0.f, 0.f, 0.f, 0.f);
        if (kg == 0) xp = E24[tok * 128 + uf4];

        float4 acc = make_float4(0.f, 0.f, 0.f, 0.f);
        if (s > 0) {
            // wait for all 32 producer waves of h(s-1) for my batch
            if (lane < 32) {
                while (__hip_atomic_load(cflg + lane, __ATOMIC_ACQUIRE,
                                         __HIP_MEMORY_SCOPE_AGENT) < s)
                    __builtin_amdgcn_s_sleep(1);
            }
            const float4* hb = hg4 + (((s - 1) & 1) * BB + bglob) * (UU / 4);
            float4 hv[8];
            #pragma unroll
            for (int j = 0; j < 8; ++j) hv[j] = hb[kg * 8 + j];
            #pragma unroll
            for (int j = 0; j < 8; ++j) {
                const float4 h4 = hv[j];
                acc.x = fmaf(h4.x, whr[4*j+0].x, acc.x);
                acc.y = fmaf(h4.x, whr[4*j+0].y, acc.y);
                acc.z = fmaf(h4.x, whr[4*j+0].z, acc.z);
                acc.w = fmaf(h4.x, whr[4*j+0].w, acc.w);
                acc.x = fmaf(h4.y, whr[4*j+1].x, acc.x);
                acc.y = fmaf(h4.y, whr[4*j+1].y, acc.y);
                acc.z = fmaf(h4.y, whr[4*j+1].z, acc.z);
                acc.w = fmaf(h4.y, whr[4*j+1].w, acc.w);
                acc.x = fmaf(h4.z, whr[4*j+2].x, acc.x);
                acc.y = fmaf(h4.z, whr[4*j+2].y, acc.y);
                acc.z = fmaf(h4.z, whr[4*j+2].z, acc.z);
                acc.w = fmaf(h4.z, whr[4*j+2].w, acc.w);
                acc.x = fmaf(h4.w, whr[4*j+3].x, acc.x);
                acc.y = fmaf(h4.w, whr[4*j+3].y, acc.y);
                acc.z = fmaf(h4.w, whr[4*j+3].z, acc.z);
                acc.w = fmaf(h4.w, whr[4*j+3].w, acc.w);
            }
        }

        // butterfly reduce over kg (lane&15)
        #pragma unroll
        for (int m = 1; m < 16; m <<= 1) {
            acc.x += __shfl_xor(acc.x, m, 64);
            acc.y += __shfl_xor(acc.y, m, 64);
            acc.z += __shfl_xor(acc.z, m, 64);
            acc.w += __shfl_xor(acc.w, m, 64);
        }

        if (kg == 0) {
            float4 hn;
            hn.x = tanh_fast(xp.x + acc.x);
            hn.y = tanh_fast(xp.y + acc.y);
            hn.z = tanh_fast(xp.z + acc.z);
            hn.w = tanh_fast(xp.w + acc.w);
            hg4[((s & 1) * BB + bglob) * (UU / 4) + uf4] = hn;
            ((float4*)hs)[(bglob * TC + tt) * (UU / 4) + uf4] = hn;
        }
        __threadfence();
        if (lane == 0)
            __hip_atomic_store(myflag, s + 1, __ATOMIC_RELEASE,
                               __HIP_MEMORY_SCOPE_AGENT);
    }
}

// ---------------- logits = hs @ Wd + bd (per chunk) ----------------
#define GM 64
#define GN 64
#define GK 16

__global__ __launch_bounds__(256) void logits_kernel(
    const float* __restrict__ A,    // [BB*TC, UU]
    const float* __restrict__ Wd,   // [UU, VV]
    const float* __restrict__ bd,   // [VV]
    float* __restrict__ out, int t0)
{
    __shared__ float As[GK][GM + 1];
    __shared__ float Bs[GK][GN + 1];
    const int tid  = threadIdx.x;
    const int row0 = blockIdx.x * GM;
    const int col0 = blockIdx.y * GN;
    const int tm = tid >> 4;
    const int tn = tid & 15;

    float acc[4][4] = {{0.f}};

    for (int k0 = 0; k0 < UU; k0 += GK) {
        #pragma unroll
        for (int i = 0; i < 4; ++i) {
            int lidx = i * 256 + tid;
            int r = lidx >> 4;
            int c = lidx & 15;
            As[c][r] = A[(row0 + r) * UU + k0 + c];
        }
        #pragma unroll
        for (int i = 0; i < 4; ++i) {
            int lidx = i * 256 + tid;
            int c = lidx >> 6;
            int n = lidx & 63;
            Bs[c][n] = Wd[(k0 + c) * VV + col0 + n];
        }
        __syncthreads();
        #pragma unroll
        for (int kk = 0; kk < GK; ++kk) {
            float av[4], bv[4];
            #pragma unroll
            for (int i = 0; i < 4; ++i) av[i] = As[kk][tm * 4 + i];
            #pragma unroll
            for (int j = 0; j < 4; ++j) bv[j] = Bs[kk][tn * 4 + j];
            #pragma unroll
            for (int i = 0; i < 4; ++i)
                #pragma unroll
                for (int j = 0; j < 4; ++j)
                    acc[i][j] = fmaf(av[i], bv[j], acc[i][j]);
        }
        __syncthreads();
    }

    #pragma unroll
    for (int i = 0; i < 4; ++i) {
        int r  = row0 + tm * 4 + i;
        int bb = r / TC;
        int tt = r & (TC - 1);
        float4 res;
        res.x = acc[i][0] + bd[col0 + tn * 4 + 0];
        res.y = acc[i][1] + bd[col0 + tn * 4 + 1];
        res.z = acc[i][2] + bd[col0 + tn * 4 + 2];
        res.w = acc[i][3] + bd[col0 + tn * 4 + 3];
        *(float4*)(out + (size_t)(bb * TT_ + t0 + tt) * VV + col0 + tn * 4) = res;
    }
}

extern "C" void kernel_launch(void* const* d_in, const int* in_sizes, int n_in,
                              void* d_out, int out_size, void* d_ws, size_t ws_size,
                              hipStream_t stream)
{
    (void)in_sizes; (void)n_in; (void)out_size; (void)ws_size;

    const int*   toks = (const int*)  d_in[0];
    const float* emb  = (const float*)d_in[1];
    const float* Wx   = (const float*)d_in[2];
    const float* Wh   = (const float*)d_in[3];
    const float* bias = (const float*)d_in[4];
    const float* Wd   = (const float*)d_in[5];
    const float* bd   = (const float*)d_in[6];
    float* out = (float*)d_out;

    // ws layout: flags (2048 int) | hglob 2*BB*UU | E2 EE*UU | hs BB*TC*UU
    int*   flg    = (int*)d_ws;
    float* hglob  = (float*)d_ws + FLG_INTS;
    float* E2     = hglob + 2 * BB * UU;
    float* hs     = E2 + EE * UU;

    hipMemsetAsync(flg, 0, FLG_INTS * sizeof(int), stream);
    e2_kernel<<<EE, UU, 0, stream>>>(emb, Wx, bias, E2);

    for (int c = 0; c < TT_ / TC; ++c) {
        const int t0 = c * TC;
        rnn_chunk_kernel<<<NBG * NUG, 512, 0, stream>>>(toks, E2, Wh, hglob, flg, hs, t0);
        logits_kernel<<<dim3((BB * TC) / GM, VV / GN), 256, 0, stream>>>(hs, Wd, bd, out, t0);
    }
}

// Round 3
// 2774.803 us; speedup vs baseline: 28.0104x; 28.0104x over previous
//
#include <hip/hip_runtime.h>
#include <math.h>

#define BB   64      // batch
#define TT_  1024    // sequence length
#define UU   512     // hidden units
#define VV   256     // vocab (output)
#define EE   256     // embedding dim
#define TC   64      // time chunk
#define NUG  8       // unit groups (64 units each)
#define NBG  32      // batch groups (2 batches each)

__device__ __forceinline__ float tanh_fast(float x) {
    // tanh(x) = 1 - 2/(e^{2x}+1); abs err ~1e-6 (validated: absmax 6e-5 end-to-end)
    float e = __expf(x + x);
    return 1.f - 2.f * __builtin_amdgcn_rcpf(e + 1.f);
}

// ---------------- E2 = emb @ Wx + b : [256, 512] ----------------
__global__ __launch_bounds__(512) void e2_kernel(
    const float* __restrict__ emb, const float* __restrict__ Wx,
    const float* __restrict__ bias, float* __restrict__ E2)
{
    const int v = blockIdx.x;
    const int u = threadIdx.x;
    float acc = bias[u];
    const float* er = emb + v * EE;
    #pragma unroll 8
    for (int e = 0; e < EE; ++e)
        acc = fmaf(er[e], Wx[e * UU + u], acc);
    E2[v * UU + u] = acc;
}

// ---------------- recurrence: Wh slice in LDS, tag-fused h exchange ----------------
// 256 blocks = 32 bg (2 batches) x 8 ug (64 units). 512 threads = 8 waves.
// Wave w owns k-slice [w*64, w*64+64). Lane: u4 = lane&15 (unit quad), kq = lane>>4.
// h published to hpub as (u32 tag=step)<<32 | f32 bits, agent-scope relaxed atomics
// (sc0|sc1 -> IF-coherent). Poll = relaxed load, NO acquire fences in the loop.
__global__ __launch_bounds__(512, 2) void rnn_chunk_kernel(
    const int* __restrict__ toks, const float* __restrict__ E2,
    const float* __restrict__ Wh, unsigned long long* hpub,  // [2][BB][UU] pairs
    float* __restrict__ hs, int t0)
{
    __shared__ float WhLDS[UU * 64];          // [k][64u] = 128 KB
    __shared__ float hstage[8][2][64];        // per-wave h staging (4 KB)
    __shared__ float partials[2][8][2][64];   // [ring][w][b][u] (8 KB)
    __shared__ int   stok[2][TC];

    const int bid  = blockIdx.x;
    const int ug   = bid & 7;
    const int bg   = bid >> 3;
    const int tid  = threadIdx.x;
    const int w    = tid >> 6;
    const int lane = tid & 63;
    const int u4   = lane & 15;
    const int kq   = lane >> 4;
    const int b0   = bg * 2;

    // ---- load Wh slice -> LDS (once per launch) ----
    const float4* Wh4  = (const float4*)Wh;   // [512][128]
    float4*       WhL4 = (float4*)WhLDS;      // [512][16]
    {
        const int col = tid & 15;             // quad within slice
        const int kr0 = tid >> 4;             // 0..31
        #pragma unroll
        for (int p = 0; p < 16; ++p) {
            int k = p * 32 + kr0;
            WhL4[k * 16 + col] = Wh4[k * 128 + ug * 16 + col];
        }
    }
    if (tid < 128) {
        int b = tid >> 6, q = tid & 63;
        stok[b][q] = toks[(b0 + b) * TT_ + t0 + q];
    }
    __syncthreads();

    for (int tt = 0; tt < TC; ++tt) {
        const int s = t0 + tt;

        // xp prefetch for reduction waves (off the critical path)
        float xp = 0.f;
        if (w < 2) xp = E2[stok[w][tt] * UU + ug * 64 + lane];

        float hreg[2][16];
        if (s > 0) {
            const int slot = (s - 1) & 1;
            unsigned long long* src0 = hpub + ((size_t)slot * BB + b0)     * UU + w * 64 + lane;
            unsigned long long* src1 = hpub + ((size_t)slot * BB + b0 + 1) * UU + w * 64 + lane;
            unsigned long long p0 = __hip_atomic_load(src0, __ATOMIC_RELAXED, __HIP_MEMORY_SCOPE_AGENT);
            unsigned long long p1 = __hip_atomic_load(src1, __ATOMIC_RELAXED, __HIP_MEMORY_SCOPE_AGENT);
            const unsigned int want = (unsigned int)(s - 1);
            while (true) {
                unsigned long long ok0 = __ballot((unsigned int)(p0 >> 32) == want);
                unsigned long long ok1 = __ballot((unsigned int)(p1 >> 32) == want);
                if ((ok0 & ok1) == 0xFFFFFFFFFFFFFFFFull) break;
                __builtin_amdgcn_s_sleep(1);
                p0 = __hip_atomic_load(src0, __ATOMIC_RELAXED, __HIP_MEMORY_SCOPE_AGENT);
                p1 = __hip_atomic_load(src1, __ATOMIC_RELAXED, __HIP_MEMORY_SCOPE_AGENT);
            }
            // stage wave's k-slice (same-wave write->read, no barrier needed)
            hstage[w][0][lane] = __uint_as_float((unsigned int)p0);
            hstage[w][1][lane] = __uint_as_float((unsigned int)p1);
            const float4* h40 = (const float4*)hstage[w][0];
            const float4* h41 = (const float4*)hstage[w][1];
            #pragma unroll
            for (int r = 0; r < 4; ++r) {
                float4 a = h40[kq * 4 + r];
                hreg[0][4*r+0] = a.x; hreg[0][4*r+1] = a.y;
                hreg[0][4*r+2] = a.z; hreg[0][4*r+3] = a.w;
                float4 c = h41[kq * 4 + r];
                hreg[1][4*r+0] = c.x; hreg[1][4*r+1] = c.y;
                hreg[1][4*r+2] = c.z; hreg[1][4*r+3] = c.w;
            }
        }

        float acc0[4] = {0.f,0.f,0.f,0.f};
        float acc1[4] = {0.f,0.f,0.f,0.f};
        if (s > 0) {
            #pragma unroll
            for (int j = 0; j < 16; ++j) {
                float4 wv = WhL4[(w * 64 + kq * 16 + j) * 16 + u4];
                float ha = hreg[0][j], hb = hreg[1][j];
                acc0[0] = fmaf(ha, wv.x, acc0[0]);
                acc0[1] = fmaf(ha, wv.y, acc0[1]);
                acc0[2] = fmaf(ha, wv.z, acc0[2]);
                acc0[3] = fmaf(ha, wv.w, acc0[3]);
                acc1[0] = fmaf(hb, wv.x, acc1[0]);
                acc1[1] = fmaf(hb, wv.y, acc1[1]);
                acc1[2] = fmaf(hb, wv.z, acc1[2]);
                acc1[3] = fmaf(hb, wv.w, acc1[3]);
            }
        }

        // reduce over kq (lanes xor 16, 32)
        #pragma unroll
        for (int i = 0; i < 4; ++i) {
            acc0[i] += __shfl_xor(acc0[i], 16, 64);
            acc0[i] += __shfl_xor(acc0[i], 32, 64);
            acc1[i] += __shfl_xor(acc1[i], 16, 64);
            acc1[i] += __shfl_xor(acc1[i], 32, 64);
        }
        if (kq == 0) {
            *(float4*)&partials[s & 1][w][0][u4 * 4] =
                make_float4(acc0[0], acc0[1], acc0[2], acc0[3]);
            *(float4*)&partials[s & 1][w][1][u4 * 4] =
                make_float4(acc1[0], acc1[1], acc1[2], acc1[3]);
        }
        __syncthreads();

        if (w < 2) {  // wave w reduces batch b0+w, all 64 units of this ug
            float ssum = xp;
            #pragma unroll
            for (int wv = 0; wv < 8; ++wv)
                ssum += partials[s & 1][wv][w][lane];
            float h = tanh_fast(ssum);
            hs[((size_t)(b0 + w) * TC + tt) * UU + ug * 64 + lane] = h;
            unsigned long long pk =
                ((unsigned long long)(unsigned int)s << 32) | __float_as_uint(h);
            __hip_atomic_store(hpub + ((size_t)(s & 1) * BB + (b0 + w)) * UU + ug * 64 + lane,
                               pk, __ATOMIC_RELAXED, __HIP_MEMORY_SCOPE_AGENT);
        }
    }
}

// ---------------- logits = hs @ Wd + bd (per chunk) ----------------
#define GM 64
#define GN 64
#define GK 16

__global__ __launch_bounds__(256) void logits_kernel(
    const float* __restrict__ A,    // [BB*TC, UU]
    const float* __restrict__ Wd,   // [UU, VV]
    const float* __restrict__ bd,   // [VV]
    float* __restrict__ out, int t0)
{
    __shared__ float As[GK][GM + 1];
    __shared__ float Bs[GK][GN + 1];
    const int tid  = threadIdx.x;
    const int row0 = blockIdx.x * GM;
    const int col0 = blockIdx.y * GN;
    const int tm = tid >> 4;
    const int tn = tid & 15;

    float acc[4][4] = {{0.f}};

    for (int k0 = 0; k0 < UU; k0 += GK) {
        #pragma unroll
        for (int i = 0; i < 4; ++i) {
            int lidx = i * 256 + tid;
            int r = lidx >> 4;
            int c = lidx & 15;
            As[c][r] = A[(row0 + r) * UU + k0 + c];
        }
        #pragma unroll
        for (int i = 0; i < 4; ++i) {
            int lidx = i * 256 + tid;
            int c = lidx >> 6;
            int n = lidx & 63;
            Bs[c][n] = Wd[(k0 + c) * VV + col0 + n];
        }
        __syncthreads();
        #pragma unroll
        for (int kk = 0; kk < GK; ++kk) {
            float av[4], bv[4];
            #pragma unroll
            for (int i = 0; i < 4; ++i) av[i] = As[kk][tm * 4 + i];
            #pragma unroll
            for (int j = 0; j < 4; ++j) bv[j] = Bs[kk][tn * 4 + j];
            #pragma unroll
            for (int i = 0; i < 4; ++i)
                #pragma unroll
                for (int j = 0; j < 4; ++j)
                    acc[i][j] = fmaf(av[i], bv[j], acc[i][j]);
        }
        __syncthreads();
    }

    #pragma unroll
    for (int i = 0; i < 4; ++i) {
        int r  = row0 + tm * 4 + i;
        int bb = r / TC;
        int tt = r & (TC - 1);
        float4 res;
        res.x = acc[i][0] + bd[col0 + tn * 4 + 0];
        res.y = acc[i][1] + bd[col0 + tn * 4 + 1];
        res.z = acc[i][2] + bd[col0 + tn * 4 + 2];
        res.w = acc[i][3] + bd[col0 + tn * 4 + 3];
        *(float4*)(out + (size_t)(bb * TT_ + t0 + tt) * VV + col0 + tn * 4) = res;
    }
}

extern "C" void kernel_launch(void* const* d_in, const int* in_sizes, int n_in,
                              void* d_out, int out_size, void* d_ws, size_t ws_size,
                              hipStream_t stream)
{
    (void)in_sizes; (void)n_in; (void)out_size; (void)ws_size;

    const int*   toks = (const int*)  d_in[0];
    const float* emb  = (const float*)d_in[1];
    const float* Wx   = (const float*)d_in[2];
    const float* Wh   = (const float*)d_in[3];
    const float* bias = (const float*)d_in[4];
    const float* Wd   = (const float*)d_in[5];
    const float* bd   = (const float*)d_in[6];
    float* out = (float*)d_out;

    // ws layout: hpub [2*BB*UU] u64 (512 KB) | E2 [EE*UU] f32 | hs [BB*TC*UU] f32
    unsigned long long* hpub = (unsigned long long*)d_ws;
    float* E2 = (float*)(hpub + 2 * BB * UU);
    float* hs = E2 + EE * UU;

    e2_kernel<<<EE, UU, 0, stream>>>(emb, Wx, bias, E2);

    for (int c = 0; c < TT_ / TC; ++c) {
        const int t0 = c * TC;
        rnn_chunk_kernel<<<NBG * NUG, 512, 0, stream>>>(toks, E2, Wh, hpub, hs, t0);
        logits_kernel<<<dim3((BB * TC) / GM, VV / GN), 256, 0, stream>>>(hs, Wd, bd, out, t0);
    }
}

// Round 4
// 2663.552 us; speedup vs baseline: 29.1804x; 1.0418x over previous
//
#include <hip/hip_runtime.h>
#include <math.h>

#define BB   64      // batch
#define TT_  1024    // sequence length
#define UU   512     // hidden units
#define VV   256     // vocab (output)
#define EE   256     // embedding dim
#define TC   64      // time chunk

__device__ __forceinline__ float tanh_fast(float x) {
    // tanh(x) = 1 - 2/(e^{2x}+1); abs err ~1e-6 (validated: absmax 6e-5 end-to-end)
    float e = __expf(x + x);
    return 1.f - 2.f * __builtin_amdgcn_rcpf(e + 1.f);
}

// ---------------- E2 = emb @ Wx + b : [256, 512] ----------------
__global__ __launch_bounds__(512) void e2_kernel(
    const float* __restrict__ emb, const float* __restrict__ Wx,
    const float* __restrict__ bias, float* __restrict__ E2)
{
    const int v = blockIdx.x;
    const int u = threadIdx.x;
    float acc = bias[u];
    const float* er = emb + v * EE;
    #pragma unroll 8
    for (int e = 0; e < EE; ++e)
        acc = fmaf(er[e], Wx[e * UU + u], acc);
    E2[v * UU + u] = acc;
}

// ---------------- fused recurrence + logits ----------------
// 256 blocks: bg = bid&31 (2 batches), ug = bid>>5 (64 units).
// bid%8 == bg%8 -> all 8 ug blocks of a batch-group share an XCD under
// round-robin dispatch (heuristic: affects SPEED only; sc1 fallback
// guarantees correctness under any mapping).
// 512 threads = 8 waves. Wave w k-slice [w*64,w*64+64); lane: u4=lane&15,
// kq=lane>>4. h published as (tag<<32|fp32) pairs: volatile(sc0, L2-local
// fast path) + agent-atomic(sc1, proven-correct fallback). Logits partials
// for step s-1 pushed via fp32 atomicAdd during the step-s exchange wait.
__global__ __launch_bounds__(512, 2) void rnn_chunk_kernel(
    const int* __restrict__ toks, const float* __restrict__ E2,
    const float* __restrict__ Wh, const float* __restrict__ Wd,
    const float* __restrict__ bd,
    unsigned long long* hpub,     // [2][BB][UU] (tag,val) pairs
    float* out, int t0, int last)
{
    __shared__ float WhLDS[UU * 64];          // [k][64u] = 128 KB
    __shared__ float hstage[8][2][64];        // per-wave h staging (4 KB)
    __shared__ float partials[2][8][2][64];   // [ring][w][b][u] (8 KB)
    __shared__ float hmine[2][2][64];         // own h slice ring (1 KB)
    __shared__ int   stok[2][TC];

    const int bid  = blockIdx.x;
    const int bg   = bid & 31;
    const int ug   = bid >> 5;
    const int tid  = threadIdx.x;
    const int w    = tid >> 6;
    const int lane = tid & 63;
    const int u4   = lane & 15;
    const int kq   = lane >> 4;
    const int b0   = bg * 2;

    // ---- Wh slice -> LDS (once per launch) ----
    const float4* Wh4  = (const float4*)Wh;   // [512][128]
    float4*       WhL4 = (float4*)WhLDS;      // [512][16]
    {
        const int col = tid & 15;
        const int kr0 = tid >> 4;
        #pragma unroll
        for (int p = 0; p < 16; ++p) {
            int k = p * 32 + kr0;
            WhL4[k * 16 + col] = Wh4[k * 128 + ug * 16 + col];
        }
    }
    if (tid < 128) {
        int b = tid >> 6, q = tid & 63;
        stok[b][q] = toks[(b0 + b) * TT_ + t0 + q];
    }
    // hmine preload: previous chunk's last h (prior dispatch completed)
    if (t0 > 0 && tid < 128) {
        int b = tid >> 6, u = tid & 63;
        unsigned long long p =
            hpub[((size_t)((t0 - 1) & 1) * BB + (b0 + b)) * UU + ug * 64 + u];
        hmine[(t0 - 1) & 1][b][u] = __uint_as_float((unsigned int)p);
    }

    // ---- Wd column -> VGPRs: thread owns (bmine, vmine) ----
    const int bmine = w & 1;
    const int vmine = (w >> 1) * 64 + lane;
    float wdreg[64];
    #pragma unroll
    for (int u = 0; u < 64; ++u)
        wdreg[u] = Wd[(ug * 64 + u) * VV + vmine];
    const float bdv = (ug == 0) ? bd[vmine] : 0.f;

    __syncthreads();

    int fails = 0;
    for (int tt = 0; tt < TC; ++tt) {
        const int s = t0 + tt;
        float xp = 0.f;
        if (w < 2) xp = E2[stok[w][tt] * UU + ug * 64 + lane];

        float acc0[4] = {0.f,0.f,0.f,0.f};
        float acc1[4] = {0.f,0.f,0.f,0.f};
        if (s > 0) {
            const int slot = (s - 1) & 1;
            const unsigned int want = (unsigned int)(s - 1);
            unsigned long long* a0 = hpub + ((size_t)slot * BB + b0) * UU + w * 64 + lane;
            unsigned long long* a1 = a0 + UU;
            unsigned long long p0 = 0, p1 = 0;
            bool got = false;
            if (fails < 3) {     // fast path: sc0 polls served by local XCD L2
                volatile const unsigned long long* f0 = a0;
                volatile const unsigned long long* f1 = a1;
                for (int it = 0; it < 24; ++it) {
                    p0 = *f0; p1 = *f1;
                    unsigned long long ok =
                        __ballot((unsigned int)(p0 >> 32) == want) &
                        __ballot((unsigned int)(p1 >> 32) == want);
                    if (ok == 0xFFFFFFFFFFFFFFFFull) { got = true; break; }
                }
                if (!got) ++fails;
            }
            if (!got) {          // fallback: R3-proven agent-scope spin
                while (true) {
                    p0 = __hip_atomic_load(a0, __ATOMIC_RELAXED, __HIP_MEMORY_SCOPE_AGENT);
                    p1 = __hip_atomic_load(a1, __ATOMIC_RELAXED, __HIP_MEMORY_SCOPE_AGENT);
                    unsigned long long ok =
                        __ballot((unsigned int)(p0 >> 32) == want) &
                        __ballot((unsigned int)(p1 >> 32) == want);
                    if (ok == 0xFFFFFFFFFFFFFFFFull) break;
                    __builtin_amdgcn_s_sleep(1);
                }
            }
            hstage[w][0][lane] = __uint_as_float((unsigned int)p0);
            hstage[w][1][lane] = __uint_as_float((unsigned int)p1);
            const float4* h40 = (const float4*)hstage[w][0];
            const float4* h41 = (const float4*)hstage[w][1];
            #pragma unroll
            for (int r = 0; r < 4; ++r) {
                float4 a = h40[kq * 4 + r];
                float4 c = h41[kq * 4 + r];
                float ha[4] = {a.x, a.y, a.z, a.w};
                float hc[4] = {c.x, c.y, c.z, c.w};
                #pragma unroll
                for (int q = 0; q < 4; ++q) {
                    float4 wv = WhL4[(w * 64 + kq * 16 + r * 4 + q) * 16 + u4];
                    acc0[0] = fmaf(ha[q], wv.x, acc0[0]);
                    acc0[1] = fmaf(ha[q], wv.y, acc0[1]);
                    acc0[2] = fmaf(ha[q], wv.z, acc0[2]);
                    acc0[3] = fmaf(ha[q], wv.w, acc0[3]);
                    acc1[0] = fmaf(hc[q], wv.x, acc1[0]);
                    acc1[1] = fmaf(hc[q], wv.y, acc1[1]);
                    acc1[2] = fmaf(hc[q], wv.z, acc1[2]);
                    acc1[3] = fmaf(hc[q], wv.w, acc1[3]);
                }
            }
        }

        // reduce over kq (lanes xor 16, 32)
        #pragma unroll
        for (int i = 0; i < 4; ++i) {
            acc0[i] += __shfl_xor(acc0[i], 16, 64);
            acc0[i] += __shfl_xor(acc0[i], 32, 64);
            acc1[i] += __shfl_xor(acc1[i], 16, 64);
            acc1[i] += __shfl_xor(acc1[i], 32, 64);
        }
        if (kq == 0) {
            *(float4*)&partials[s & 1][w][0][u4 * 4] =
                make_float4(acc0[0], acc0[1], acc0[2], acc0[3]);
            *(float4*)&partials[s & 1][w][1][u4 * 4] =
                make_float4(acc1[0], acc1[1], acc1[2], acc1[3]);
        }
        __syncthreads();

        if (w < 2) {   // finalize h(s) for batch b0+w, publish ASAP
            float ssum = xp;
            #pragma unroll
            for (int wv = 0; wv < 8; ++wv)
                ssum += partials[s & 1][wv][w][lane];
            float h = tanh_fast(ssum);
            unsigned long long pk =
                ((unsigned long long)(unsigned int)s << 32) | __float_as_uint(h);
            unsigned long long* dst =
                hpub + ((size_t)(s & 1) * BB + (b0 + w)) * UU + ug * 64 + lane;
            *(volatile unsigned long long*)dst = pk;   // sc0 local-L2 copy
            __hip_atomic_store(dst, pk, __ATOMIC_RELAXED, __HIP_MEMORY_SCOPE_AGENT);
            hmine[s & 1][w][lane] = h;
        }

        // logits partial for step s-1 (all waves; hidden in exchange wait)
        if (s > 0) {
            const float4* hb = (const float4*)hmine[(s - 1) & 1][bmine];
            float sum = bdv;
            #pragma unroll
            for (int j = 0; j < 16; ++j) {
                float4 h4 = hb[j];
                sum = fmaf(h4.x, wdreg[4*j+0], sum);
                sum = fmaf(h4.y, wdreg[4*j+1], sum);
                sum = fmaf(h4.z, wdreg[4*j+2], sum);
                sum = fmaf(h4.w, wdreg[4*j+3], sum);
            }
            atomicAdd(out + ((size_t)(b0 + bmine) * TT_ + (s - 1)) * VV + vmine, sum);
        }
    }

    if (last) {   // final chunk: logits for s = 1023
        __syncthreads();
        const int s = t0 + TC - 1;
        const float4* hb = (const float4*)hmine[s & 1][bmine];
        float sum = bdv;
        #pragma unroll
        for (int j = 0; j < 16; ++j) {
            float4 h4 = hb[j];
            sum = fmaf(h4.x, wdreg[4*j+0], sum);
            sum = fmaf(h4.y, wdreg[4*j+1], sum);
            sum = fmaf(h4.z, wdreg[4*j+2], sum);
            sum = fmaf(h4.w, wdreg[4*j+3], sum);
        }
        atomicAdd(out + ((size_t)(b0 + bmine) * TT_ + s) * VV + vmine, sum);
    }
}

extern "C" void kernel_launch(void* const* d_in, const int* in_sizes, int n_in,
                              void* d_out, int out_size, void* d_ws, size_t ws_size,
                              hipStream_t stream)
{
    (void)in_sizes; (void)n_in; (void)ws_size;

    const int*   toks = (const int*)  d_in[0];
    const float* emb  = (const float*)d_in[1];
    const float* Wx   = (const float*)d_in[2];
    const float* Wh   = (const float*)d_in[3];
    const float* bias = (const float*)d_in[4];
    const float* Wd   = (const float*)d_in[5];
    const float* bd   = (const float*)d_in[6];
    float* out = (float*)d_out;

    // ws layout: hpub [2*BB*UU] u64 (512 KB) | E2 [EE*UU] f32 (512 KB)
    unsigned long long* hpub = (unsigned long long*)d_ws;
    float* E2 = (float*)(hpub + 2 * BB * UU);

    hipMemsetAsync(out, 0, (size_t)out_size * sizeof(float), stream);
    e2_kernel<<<EE, UU, 0, stream>>>(emb, Wx, bias, E2);

    for (int c = 0; c < TT_ / TC; ++c) {
        const int t0 = c * TC;
        rnn_chunk_kernel<<<256, 512, 0, stream>>>(
            toks, E2, Wh, Wd, bd, hpub, out, t0, c == (TT_ / TC - 1));
    }
}